// Round 1
// baseline (890.314 us; speedup 1.0000x reference)
//
#include <hip/hip_runtime.h>
#include <stdint.h>

// HashedEmbeddingBag: out[b][d] = sum_{i<50} weight[(idx[b][i]*P1 + d*P2) % WS]
// WS = 2,000,000; B = 16384; L = 50; D = 128.
//
// Strategy: 1 block (128 threads) per bag; thread = dim.
//  - threads 0..49 compute a_i = (idx_i * P1) % WS once (64-bit mod) -> LDS
//  - each thread holds c_d = (d * (P2 % WS)) % WS (32-bit, computed once)
//  - inner loop: h = a_i + c_d (mod WS via compare-subtract), gather, accumulate.
// Gathers are random within an 8MB table -> L2/L3 resident, request-rate bound.

#define WS 2000000u
#define EMB_DIM 128
#define BAG_LEN 50
#define BATCH 16384

__global__ __launch_bounds__(128) void heb_gather_sum(
    const float* __restrict__ weight,
    const int*   __restrict__ indices,
    float*       __restrict__ out)
{
    __shared__ uint32_t a_sm[BAG_LEN];

    const int bag = blockIdx.x;
    const int d   = threadIdx.x;

    // Stage per-index hash bases (once per bag).
    if (d < BAG_LEN) {
        const uint64_t P1 = 9824516537ull;
        uint64_t idx = (uint64_t)(uint32_t)indices[bag * BAG_LEN + d];
        a_sm[d] = (uint32_t)((idx * P1) % (uint64_t)WS);
    }
    __syncthreads();

    // Per-dim offset: P2 % WS == 300227; d*300227 < 2^26 so 32-bit math is exact.
    const uint32_t c = ((uint32_t)d * 300227u) % WS;

    float sum = 0.0f;
#pragma unroll
    for (int i = 0; i < BAG_LEN; ++i) {
        uint32_t h = a_sm[i] + c;          // < 2*WS
        if (h >= WS) h -= WS;              // full mod
        sum += weight[h];
    }

    out[bag * EMB_DIM + d] = sum;
}

extern "C" void kernel_launch(void* const* d_in, const int* in_sizes, int n_in,
                              void* d_out, int out_size, void* d_ws, size_t ws_size,
                              hipStream_t stream)
{
    const float* weight  = (const float*)d_in[0];   // [2,000,000] fp32
    const int*   indices = (const int*)d_in[1];     // [16384*50] int
    float*       out     = (float*)d_out;           // [16384*128] fp32

    heb_gather_sum<<<BATCH, EMB_DIM, 0, stream>>>(weight, indices, out);
}

// Round 2
// 728.138 us; speedup vs baseline: 1.2227x; 1.2227x over previous
//
#include <hip/hip_runtime.h>
#include <stdint.h>

// HashedEmbeddingBag: out[b][d] = sum_{i<50} weight[(idx[b][i]*P1 + d*P2) % WS]
// WS = 2,000,000; B = 16384; L = 50; D = 128.
//
// R1: hash-space region blocking. The 8MB table doesn't fit a 4MiB per-XCD
// L2 -> R0 fetched 3.2GB from HBM (random 4B-of-64B-line reads, ~50% L2
// miss). Sweep the table in NREG=4 regions of 2MB each; all blocks do
// regions in the same order, so each XCD's L2 holds the active 2MB region
// and gathers become L2 hits. Gathers are predicated (exec-masked) on
// h in region -> same total line requests, 4x the (negligible) VALU work.

#define WS        2000000u
#define EMB_DIM   128
#define BAG_LEN   50
#define BATCH     16384
#define NREG      4
#define REG_SIZE  (WS / NREG)   // 500,000 elements = 2MB per region

__global__ __launch_bounds__(128) void heb_gather_sum(
    const float* __restrict__ weight,
    const int*   __restrict__ indices,
    float*       __restrict__ out)
{
    __shared__ uint32_t a_sm[BAG_LEN];

    const int bag = blockIdx.x;
    const int d   = threadIdx.x;

    // Stage per-index hash bases (once per bag).
    if (d < BAG_LEN) {
        const uint64_t P1 = 9824516537ull;
        uint64_t idx = (uint64_t)(uint32_t)indices[bag * BAG_LEN + d];
        a_sm[d] = (uint32_t)((idx * P1) % (uint64_t)WS);
    }
    __syncthreads();

    // Per-dim offset: P2 % WS == 300227; d*300227 < 2^26 so 32-bit is exact.
    const uint32_t c = ((uint32_t)d * 300227u) % WS;

    float sum = 0.0f;
    for (uint32_t lo = 0; lo < WS; lo += REG_SIZE) {   // region sweep
        const uint32_t hi = lo + REG_SIZE;
#pragma unroll
        for (int i = 0; i < BAG_LEN; ++i) {
            uint32_t h = a_sm[i] + c;       // < 2*WS
            if (h >= WS) h -= WS;           // full mod
            if (h >= lo && h < hi) {        // exec-masked gather
                sum += weight[h];
            }
        }
    }

    out[bag * EMB_DIM + d] = sum;
}

extern "C" void kernel_launch(void* const* d_in, const int* in_sizes, int n_in,
                              void* d_out, int out_size, void* d_ws, size_t ws_size,
                              hipStream_t stream)
{
    const float* weight  = (const float*)d_in[0];   // [2,000,000] fp32
    const int*   indices = (const int*)d_in[1];     // [16384*50] int
    float*       out     = (float*)d_out;           // [16384*128] fp32

    heb_gather_sum<<<BATCH, EMB_DIM, 0, stream>>>(weight, indices, out);
}